// Round 9
// baseline (553.575 us; speedup 1.0000x reference)
//
#include <hip/hip_runtime.h>
#include <math.h>

#define NN 50000
#define EE 800000
#define INC 128
#define HIDC 64
#define OUTC 64
#define LLAYERS 8
#define TOT (EE + NN)
#define SCAN_B 200   // ceil(NN/256)

// Wave-internal LDS fence: orders this wave's ds_write -> ds_read without a
// block barrier (vecs[w] is private to wave w; no cross-wave sharing).
#define WAVE_LDS_FENCE() asm volatile("s_waitcnt lgkmcnt(0)" ::: "memory")

// ---------------------------------------------------------------------------
// Stage 0: detect whether edge_index was delivered as int64 or int32.
__global__ void detect_kernel(const long long* __restrict__ p, int* __restrict__ flag) {
    int stride = gridDim.x * blockDim.x;
    int bad = 0;
    for (int i = blockIdx.x * blockDim.x + threadIdx.x; i < EE; i += stride) {
        long long v = p[i];
        bad |= (v < 0 || v >= NN);
    }
    if (bad) atomicOr(flag, 1);   // flag=1 -> int32 layout
}

__device__ __forceinline__ int load_row(const void* ei, int is64, int e) {
    return is64 ? (int)((const long long*)ei)[e] : ((const int*)ei)[e];
}
__device__ __forceinline__ int load_col(const void* ei, int is64, int e) {
    return is64 ? (int)((const long long*)ei)[EE + e] : ((const int*)ei)[EE + e];
}

// Stage 1: in-degree of col (self-loops included)
__global__ void deg_kernel(const void* __restrict__ ei, const int* __restrict__ flag,
                           int* __restrict__ degi) {
    int i = blockIdx.x * blockDim.x + threadIdx.x;
    if (i >= TOT) return;
    int is64 = (*flag == 0);
    int c = (i < EE) ? load_col(ei, is64, i) : (i - EE);
    atomicAdd(&degi[c], 1);
}

__global__ void dinv_kernel(const int* __restrict__ degi, float* __restrict__ dinv) {
    int i = blockIdx.x * blockDim.x + threadIdx.x;
    if (i < NN) {
        int d = degi[i];
        dinv[i] = d > 0 ? 1.0f / sqrtf((float)d) : 0.0f;
    }
}

// ---------------------------------------------------------------------------
// Stage 2: 3-kernel device-wide exclusive scan
__global__ __launch_bounds__(256) void scan_part(const int* __restrict__ degi,
                                                 int* __restrict__ bsum) {
    __shared__ int s[256];
    int t = threadIdx.x;
    int i = blockIdx.x * 256 + t;
    s[t] = (i < NN) ? degi[i] : 0;
    __syncthreads();
    for (int off = 128; off > 0; off >>= 1) {
        if (t < off) s[t] += s[t + off];
        __syncthreads();
    }
    if (t == 0) bsum[blockIdx.x] = s[0];
}

__global__ __launch_bounds__(256) void scan_bsum(int* __restrict__ bsum) {
    __shared__ int s[256];
    int t = threadIdx.x;
    int v = (t < SCAN_B) ? bsum[t] : 0;
    s[t] = v;
    __syncthreads();
    for (int off = 1; off < 256; off <<= 1) {
        int add = (t >= off) ? s[t - off] : 0;
        __syncthreads();
        s[t] += add;
        __syncthreads();
    }
    if (t < SCAN_B) bsum[t] = s[t] - v;   // exclusive
}

__global__ __launch_bounds__(256) void scan_final(const int* __restrict__ degi,
                                                  const int* __restrict__ bsum,
                                                  int* __restrict__ offsets) {
    __shared__ int s[256];
    int t = threadIdx.x;
    int i = blockIdx.x * 256 + t;
    int v = (i < NN) ? degi[i] : 0;
    s[t] = v;
    __syncthreads();
    for (int off = 1; off < 256; off <<= 1) {
        int add = (t >= off) ? s[t - off] : 0;
        __syncthreads();
        s[t] += add;
        __syncthreads();
    }
    if (i < NN) {
        int off_i = bsum[blockIdx.x] + s[t] - v;   // exclusive prefix of degi[i]
        offsets[i] = off_i;
        if (i == NN - 1) offsets[NN] = off_i + v;
    }
}

// Stage 3: fill CSR adjacency (src, norm) sorted by destination
__global__ void fill_kernel(const void* __restrict__ ei, const int* __restrict__ flag,
                            const float* __restrict__ dinv, int* __restrict__ cursor,
                            int2* __restrict__ adj) {
    int i = blockIdx.x * blockDim.x + threadIdx.x;
    if (i >= TOT) return;
    int is64 = (*flag == 0);
    int r, c;
    if (i < EE) { r = load_row(ei, is64, i); c = load_col(ei, is64, i); }
    else        { r = i - EE; c = r; }
    int pos = atomicAdd(&cursor[c], 1);
    adj[pos] = make_int2(r, __float_as_int(dinv[r] * dinv[c]));
}

// Stage 4: h = relu(x @ w_in^T + b_in); also x0 = h.
// 512 threads (8 waves) share ONE wT copy: 36KB LDS -> 4 blocks/CU -> 32
// waves/CU (100%), vs 256-thread version capped at 50% by 34.5KB/block.
__global__ __launch_bounds__(512) void in_gemm(const float* __restrict__ x,
                                               const float* __restrict__ w_in,
                                               const float* __restrict__ b_in,
                                               float* __restrict__ h,
                                               float* __restrict__ x0) {
    __shared__ float wT[INC * 64];   // [k*64 + j]; lane-consecutive reads: conflict-free
    __shared__ float xs[8][INC];
    int tid = threadIdx.x;
    for (int i = tid; i < HIDC * INC; i += 512) {
        int j = i >> 7, k = i & 127;          // w_in[j][k], row-major [64][128]
        wT[k * 64 + j] = w_in[i];
    }
    __syncthreads();
    int w = tid >> 6, lane = tid & 63;
    float bj = b_in[lane];
    for (int n0 = blockIdx.x * 8; n0 < NN; n0 += gridDim.x * 8) {
        int n = n0 + w;
        if (n < NN) {
            xs[w][lane]      = x[(size_t)n * INC + lane];
            xs[w][lane + 64] = x[(size_t)n * INC + 64 + lane];
            WAVE_LDS_FENCE();
            float acc = bj;
            #pragma unroll 8
            for (int k = 0; k < INC; ++k)
                acc = fmaf(xs[w][k], wT[(k << 6) + lane], acc);
            float v = fmaxf(acc, 0.0f);
            h[(size_t)n * HIDC + lane]  = v;
            x0[(size_t)n * HIDC + lane] = v;
        }
    }
}

// ---------------------------------------------------------------------------
// Gather core v2: wave handles node n. lane = g*8 + c (g = edge-group 0..7,
// c = channel-octet 0..7). Group g walks edges e0+g, e0+g+8, ... Each lane
// loads 2 float4s (channels c*8..c*8+7). Per unrolled step: 16 distinct h
// rows in flight (vs 8 in the 4-group version) -- MLP doubled to probe the
// latency-vs-L3-BW question.
__device__ __forceinline__ void gather_node8(const float* __restrict__ h_in,
                                             const int2* __restrict__ adj,
                                             int e0, int e1, int g, int c,
                                             float4& acc0, float4& acc1) {
    acc0 = make_float4(0.f, 0.f, 0.f, 0.f);
    acc1 = make_float4(0.f, 0.f, 0.f, 0.f);
    #pragma unroll 2
    for (int e = e0 + g; e < e1; e += 8) {
        int2 a = adj[e];
        const float* row = h_in + ((a.x << 6) + (c << 3));
        float4 h0 = *reinterpret_cast<const float4*>(row);
        float4 h1 = *reinterpret_cast<const float4*>(row + 4);
        float nrm = __int_as_float(a.y);
        acc0.x = fmaf(nrm, h0.x, acc0.x); acc0.y = fmaf(nrm, h0.y, acc0.y);
        acc0.z = fmaf(nrm, h0.z, acc0.z); acc0.w = fmaf(nrm, h0.w, acc0.w);
        acc1.x = fmaf(nrm, h1.x, acc1.x); acc1.y = fmaf(nrm, h1.y, acc1.y);
        acc1.z = fmaf(nrm, h1.z, acc1.z); acc1.w = fmaf(nrm, h1.w, acc1.w);
    }
    // reduce across the 8 groups (lane bits 3..5)
    #pragma unroll
    for (int m = 8; m <= 32; m <<= 1) {
        acc0.x += __shfl_xor(acc0.x, m); acc0.y += __shfl_xor(acc0.y, m);
        acc0.z += __shfl_xor(acc0.z, m); acc0.w += __shfl_xor(acc0.w, m);
        acc1.x += __shfl_xor(acc1.x, m); acc1.y += __shfl_xor(acc1.y, m);
        acc1.z += __shfl_xor(acc1.z, m); acc1.w += __shfl_xor(acc1.w, m);
    }
}

// Stage 5: GCNII layer (all 8 layers). Waves fully decoupled (no per-iter
// block barrier; vecs[w] is wave-private, ordered by lgkmcnt fence).
__global__ __launch_bounds__(256, 8) void layer_mid(
        const float* __restrict__ h_in, float* __restrict__ h_out,
        const float* __restrict__ x0,
        const int* __restrict__ offsets, const int2* __restrict__ adj,
        const float* __restrict__ W, float beta) {
    __shared__ float WT[HIDC * 65];
    __shared__ float vecs[4][HIDC];
    int tid = threadIdx.x;
    for (int i = tid; i < HIDC * HIDC; i += 256) {
        int j = i >> 6, k = i & 63;
        WT[k * 65 + j] = W[i];
    }
    __syncthreads();
    int w = tid >> 6, lane = tid & 63;
    int g = lane >> 3, c = lane & 7;
    float omb = 1.0f - beta;

    for (int n0 = blockIdx.x * 4; n0 < NN; n0 += gridDim.x * 4) {
        int n = n0 + w;
        if (n < NN) {                          // uniform per wave
            int e0 = offsets[n], e1 = offsets[n + 1];
            float4 acc0, acc1;
            gather_node8(h_in, adj, e0, e1, g, c, acc0, acc1);
            if (g == 0) {                      // lanes 0..7 hold the full sums
                const float* x0p = x0 + ((n << 6) + (c << 3));
                float4 x0a = *reinterpret_cast<const float4*>(x0p);
                float4 x0b = *reinterpret_cast<const float4*>(x0p + 4);
                float4 va, vb;
                va.x = fmaf(0.9f, acc0.x, 0.1f * x0a.x);
                va.y = fmaf(0.9f, acc0.y, 0.1f * x0a.y);
                va.z = fmaf(0.9f, acc0.z, 0.1f * x0a.z);
                va.w = fmaf(0.9f, acc0.w, 0.1f * x0a.w);
                vb.x = fmaf(0.9f, acc1.x, 0.1f * x0b.x);
                vb.y = fmaf(0.9f, acc1.y, 0.1f * x0b.y);
                vb.z = fmaf(0.9f, acc1.z, 0.1f * x0b.z);
                vb.w = fmaf(0.9f, acc1.w, 0.1f * x0b.w);
                *reinterpret_cast<float4*>(&vecs[w][c << 3])       = va;
                *reinterpret_cast<float4*>(&vecs[w][(c << 3) + 4]) = vb;
            }
            WAVE_LDS_FENCE();
            float vagg = vecs[w][lane];
            float dot = 0.0f;
            #pragma unroll 8
            for (int k = 0; k < HIDC; ++k)
                dot = fmaf(vecs[w][k], WT[k * 65 + lane], dot);
            float hn = fmaxf(fmaf(beta, dot, omb * vagg), 0.0f);
            h_out[(n << 6) + lane] = hn;
        }
    }
}

// Stage 6: out = h @ w_out^T + b_out.
__global__ __launch_bounds__(256, 8) void out_gemm(const float* __restrict__ h,
                                                   const float* __restrict__ w_out,
                                                   const float* __restrict__ b_out,
                                                   float* __restrict__ out) {
    __shared__ float WoT[HIDC * 65];
    __shared__ float vecs[4][HIDC];
    int tid = threadIdx.x;
    for (int i = tid; i < HIDC * HIDC; i += 256) {
        int j = i >> 6, k = i & 63;
        WoT[k * 65 + j] = w_out[i];
    }
    __syncthreads();
    int w = tid >> 6, lane = tid & 63;
    float bj = b_out[lane];
    for (int n0 = blockIdx.x * 4; n0 < NN; n0 += gridDim.x * 4) {
        int n = n0 + w;
        if (n < NN) {
            vecs[w][lane] = h[(n << 6) + lane];
            WAVE_LDS_FENCE();
            float acc = bj;
            #pragma unroll 8
            for (int k = 0; k < HIDC; ++k)
                acc = fmaf(vecs[w][k], WoT[k * 65 + lane], acc);
            out[(n << 6) + lane] = acc;
        }
    }
}

extern "C" void kernel_launch(void* const* d_in, const int* in_sizes, int n_in,
                              void* d_out, int out_size, void* d_ws, size_t ws_size,
                              hipStream_t stream) {
    const float* x      = (const float*)d_in[0];
    const void*  ei     = d_in[1];
    const float* w_in   = (const float*)d_in[2];
    const float* b_in   = (const float*)d_in[3];
    const float* conv_w = (const float*)d_in[4];
    const float* w_out  = (const float*)d_in[5];
    const float* b_out  = (const float*)d_in[6];
    float* out = (float*)d_out;

    char* ws = (char*)d_ws;
    size_t off = 0;
    auto alloc = [&](size_t bytes) -> void* {
        void* p = ws + off;
        off += (bytes + 255) & ~(size_t)255;
        return p;
    };
    int*   flag    = (int*)alloc(4);
    int*   degi    = (int*)alloc((size_t)NN * 4);
    float* dinv    = (float*)alloc((size_t)NN * 4);
    int*   offsets = (int*)alloc((size_t)(NN + 1) * 4);
    int*   cursor  = (int*)alloc((size_t)NN * 4);
    int*   bsum    = (int*)alloc((size_t)SCAN_B * 4);
    int2*  adj     = (int2*)alloc((size_t)TOT * 8);
    float* hA      = (float*)alloc((size_t)NN * HIDC * 4);
    float* hB      = (float*)alloc((size_t)NN * HIDC * 4);
    float* x0      = (float*)alloc((size_t)NN * HIDC * 4);

    hipMemsetAsync(flag, 0, 4, stream);
    hipMemsetAsync(degi, 0, (size_t)NN * 4, stream);
    detect_kernel<<<256, 256, 0, stream>>>((const long long*)ei, flag);
    deg_kernel<<<(TOT + 255) / 256, 256, 0, stream>>>(ei, flag, degi);
    dinv_kernel<<<(NN + 255) / 256, 256, 0, stream>>>(degi, dinv);
    scan_part<<<SCAN_B, 256, 0, stream>>>(degi, bsum);
    scan_bsum<<<1, 256, 0, stream>>>(bsum);
    scan_final<<<SCAN_B, 256, 0, stream>>>(degi, bsum, offsets);
    hipMemcpyAsync(cursor, offsets, (size_t)NN * 4, hipMemcpyDeviceToDevice, stream);
    fill_kernel<<<(TOT + 255) / 256, 256, 0, stream>>>(ei, flag, dinv, cursor, adj);
    in_gemm<<<2048, 512, 0, stream>>>(x, w_in, b_in, hA, x0);

    float* cur = hA;
    float* nxt = hB;
    for (int l = 0; l < LLAYERS; ++l) {
        float beta = logf(0.5f / (float)(l + 1) + 1.0f);
        const float* Wl = conv_w + (size_t)l * HIDC * HIDC;
        layer_mid<<<2048, 256, 0, stream>>>(cur, nxt, x0, offsets, adj, Wl, beta);
        float* t = cur; cur = nxt; nxt = t;
    }
    out_gemm<<<1024, 256, 0, stream>>>(cur, w_out, b_out, out);
}

// Round 10
// 475.279 us; speedup vs baseline: 1.1647x; 1.1647x over previous
//
#include <hip/hip_runtime.h>
#include <math.h>

#define NN 50000
#define EE 800000
#define INC 128
#define HIDC 64
#define OUTC 64
#define LLAYERS 8
#define TOT (EE + NN)
#define SCAN_B 200   // ceil(NN/256)

// Wave-internal LDS fence: orders this wave's ds_write -> ds_read without a
// block barrier (vecs[w]/xs[w] is private to wave w; no cross-wave sharing).
#define WAVE_LDS_FENCE() asm volatile("s_waitcnt lgkmcnt(0)" ::: "memory")

// ---------------------------------------------------------------------------
// Stage 0: detect whether edge_index was delivered as int64 or int32.
__global__ void detect_kernel(const long long* __restrict__ p, int* __restrict__ flag) {
    int stride = gridDim.x * blockDim.x;
    int bad = 0;
    for (int i = blockIdx.x * blockDim.x + threadIdx.x; i < EE; i += stride) {
        long long v = p[i];
        bad |= (v < 0 || v >= NN);
    }
    if (bad) atomicOr(flag, 1);   // flag=1 -> int32 layout
}

__device__ __forceinline__ int load_row(const void* ei, int is64, int e) {
    return is64 ? (int)((const long long*)ei)[e] : ((const int*)ei)[e];
}
__device__ __forceinline__ int load_col(const void* ei, int is64, int e) {
    return is64 ? (int)((const long long*)ei)[EE + e] : ((const int*)ei)[EE + e];
}

// Stage 1: in-degree of col (self-loops included)
__global__ void deg_kernel(const void* __restrict__ ei, const int* __restrict__ flag,
                           int* __restrict__ degi) {
    int i = blockIdx.x * blockDim.x + threadIdx.x;
    if (i >= TOT) return;
    int is64 = (*flag == 0);
    int c = (i < EE) ? load_col(ei, is64, i) : (i - EE);
    atomicAdd(&degi[c], 1);
}

__global__ void dinv_kernel(const int* __restrict__ degi, float* __restrict__ dinv) {
    int i = blockIdx.x * blockDim.x + threadIdx.x;
    if (i < NN) {
        int d = degi[i];
        dinv[i] = d > 0 ? 1.0f / sqrtf((float)d) : 0.0f;
    }
}

// ---------------------------------------------------------------------------
// Stage 2: 3-kernel device-wide exclusive scan
__global__ __launch_bounds__(256) void scan_part(const int* __restrict__ degi,
                                                 int* __restrict__ bsum) {
    __shared__ int s[256];
    int t = threadIdx.x;
    int i = blockIdx.x * 256 + t;
    s[t] = (i < NN) ? degi[i] : 0;
    __syncthreads();
    for (int off = 128; off > 0; off >>= 1) {
        if (t < off) s[t] += s[t + off];
        __syncthreads();
    }
    if (t == 0) bsum[blockIdx.x] = s[0];
}

__global__ __launch_bounds__(256) void scan_bsum(int* __restrict__ bsum) {
    __shared__ int s[256];
    int t = threadIdx.x;
    int v = (t < SCAN_B) ? bsum[t] : 0;
    s[t] = v;
    __syncthreads();
    for (int off = 1; off < 256; off <<= 1) {
        int add = (t >= off) ? s[t - off] : 0;
        __syncthreads();
        s[t] += add;
        __syncthreads();
    }
    if (t < SCAN_B) bsum[t] = s[t] - v;   // exclusive
}

__global__ __launch_bounds__(256) void scan_final(const int* __restrict__ degi,
                                                  const int* __restrict__ bsum,
                                                  int* __restrict__ offsets) {
    __shared__ int s[256];
    int t = threadIdx.x;
    int i = blockIdx.x * 256 + t;
    int v = (i < NN) ? degi[i] : 0;
    s[t] = v;
    __syncthreads();
    for (int off = 1; off < 256; off <<= 1) {
        int add = (t >= off) ? s[t - off] : 0;
        __syncthreads();
        s[t] += add;
        __syncthreads();
    }
    if (i < NN) {
        int off_i = bsum[blockIdx.x] + s[t] - v;   // exclusive prefix of degi[i]
        offsets[i] = off_i;
        if (i == NN - 1) offsets[NN] = off_i + v;
    }
}

// Stage 3: fill CSR adjacency (src, norm) sorted by destination
__global__ void fill_kernel(const void* __restrict__ ei, const int* __restrict__ flag,
                            const float* __restrict__ dinv, int* __restrict__ cursor,
                            int2* __restrict__ adj) {
    int i = blockIdx.x * blockDim.x + threadIdx.x;
    if (i >= TOT) return;
    int is64 = (*flag == 0);
    int r, c;
    if (i < EE) { r = load_row(ei, is64, i); c = load_col(ei, is64, i); }
    else        { r = i - EE; c = r; }
    int pos = atomicAdd(&cursor[c], 1);
    adj[pos] = make_int2(r, __float_as_int(dinv[r] * dinv[c]));
}

// Stage 4: h = relu(x @ w_in^T + b_in); also x0 = h.
// 512 threads (8 waves) share ONE wT copy with the PROVEN 65-pad layout
// (bank = (k + j) % 32 on the staging write -> conflict-free; R9's unpadded
// stride-64 layout put all 64 lanes in one bank = 1.6e7 conflict cycles).
// 33.3KB wT + 4KB xs = 37.4KB -> 4 blocks/CU x 8 waves = 100% occ ceiling.
__global__ __launch_bounds__(512) void in_gemm(const float* __restrict__ x,
                                               const float* __restrict__ w_in,
                                               const float* __restrict__ b_in,
                                               float* __restrict__ h,
                                               float* __restrict__ x0) {
    __shared__ float wT[INC * 65];
    __shared__ float xs[8][INC];
    int tid = threadIdx.x;
    for (int i = tid; i < HIDC * INC; i += 512) {
        int j = i >> 7, k = i & 127;          // w_in[j][k], row-major [64][128]
        wT[k * 65 + j] = w_in[i];
    }
    __syncthreads();
    int w = tid >> 6, lane = tid & 63;
    float bj = b_in[lane];
    for (int n0 = blockIdx.x * 8; n0 < NN; n0 += gridDim.x * 8) {
        int n = n0 + w;
        if (n < NN) {
            xs[w][lane]      = x[(size_t)n * INC + lane];
            xs[w][lane + 64] = x[(size_t)n * INC + 64 + lane];
            WAVE_LDS_FENCE();
            float acc = bj;
            #pragma unroll 8
            for (int k = 0; k < INC; ++k)
                acc = fmaf(xs[w][k], wT[k * 65 + lane], acc);
            float v = fmaxf(acc, 0.0f);
            h[(size_t)n * HIDC + lane]  = v;
            x0[(size_t)n * HIDC + lane] = v;
        }
    }
}

// ---------------------------------------------------------------------------
// Gather core (reverted to R8's 4-group version -- R9's 8-group x 2-float4
// variant cost +7.5us/layer: same distinct-row MLP per instruction, 3x the
// shuffles). Wave handles node n. lane = g*16 + c. Each vector-load
// instruction fetches FOUR distinct h rows (4 x 256B = 1KB).
__device__ __forceinline__ float4 gather_node(const float* __restrict__ h_in,
                                              const int2* __restrict__ adj,
                                              int e0, int e1, int g, int c) {
    float4 acc = make_float4(0.f, 0.f, 0.f, 0.f);
    #pragma unroll 2
    for (int e = e0 + g; e < e1; e += 4) {
        int2 a = adj[e];
        const float4 hv = *reinterpret_cast<const float4*>(h_in + ((a.x << 6) + (c << 2)));
        float nrm = __int_as_float(a.y);
        acc.x = fmaf(nrm, hv.x, acc.x);
        acc.y = fmaf(nrm, hv.y, acc.y);
        acc.z = fmaf(nrm, hv.z, acc.z);
        acc.w = fmaf(nrm, hv.w, acc.w);
    }
    // reduce across the 4 groups (lanes differing in bits 4..5)
    acc.x += __shfl_xor(acc.x, 16); acc.y += __shfl_xor(acc.y, 16);
    acc.z += __shfl_xor(acc.z, 16); acc.w += __shfl_xor(acc.w, 16);
    acc.x += __shfl_xor(acc.x, 32); acc.y += __shfl_xor(acc.y, 32);
    acc.z += __shfl_xor(acc.z, 32); acc.w += __shfl_xor(acc.w, 32);
    return acc;
}

// Stage 5: GCNII layer (all 8 layers). Waves fully decoupled (no per-iter
// block barrier; vecs[w] is wave-private, ordered by lgkmcnt fence).
__global__ __launch_bounds__(256, 8) void layer_mid(
        const float* __restrict__ h_in, float* __restrict__ h_out,
        const float* __restrict__ x0,
        const int* __restrict__ offsets, const int2* __restrict__ adj,
        const float* __restrict__ W, float beta) {
    __shared__ float WT[HIDC * 65];
    __shared__ float vecs[4][HIDC];
    int tid = threadIdx.x;
    for (int i = tid; i < HIDC * HIDC; i += 256) {
        int j = i >> 6, k = i & 63;
        WT[k * 65 + j] = W[i];
    }
    __syncthreads();
    int w = tid >> 6, lane = tid & 63;
    int g = lane >> 4, c = lane & 15;
    float omb = 1.0f - beta;

    for (int n0 = blockIdx.x * 4; n0 < NN; n0 += gridDim.x * 4) {
        int n = n0 + w;
        if (n < NN) {                          // uniform per wave
            int e0 = offsets[n], e1 = offsets[n + 1];
            float4 acc = gather_node(h_in, adj, e0, e1, g, c);
            if (g == 0) {
                const float4 x0v = *reinterpret_cast<const float4*>(x0 + ((n << 6) + (c << 2)));
                float4 aggv;
                aggv.x = fmaf(0.9f, acc.x, 0.1f * x0v.x);
                aggv.y = fmaf(0.9f, acc.y, 0.1f * x0v.y);
                aggv.z = fmaf(0.9f, acc.z, 0.1f * x0v.z);
                aggv.w = fmaf(0.9f, acc.w, 0.1f * x0v.w);
                *reinterpret_cast<float4*>(&vecs[w][c << 2]) = aggv;
            }
            WAVE_LDS_FENCE();
            float vagg = vecs[w][lane];
            float dot = 0.0f;
            #pragma unroll 8
            for (int k = 0; k < HIDC; ++k)
                dot = fmaf(vecs[w][k], WT[k * 65 + lane], dot);
            float hn = fmaxf(fmaf(beta, dot, omb * vagg), 0.0f);
            h_out[(n << 6) + lane] = hn;
        }
    }
}

// Stage 6: out = h @ w_out^T + b_out.
__global__ __launch_bounds__(256, 8) void out_gemm(const float* __restrict__ h,
                                                   const float* __restrict__ w_out,
                                                   const float* __restrict__ b_out,
                                                   float* __restrict__ out) {
    __shared__ float WoT[HIDC * 65];
    __shared__ float vecs[4][HIDC];
    int tid = threadIdx.x;
    for (int i = tid; i < HIDC * HIDC; i += 256) {
        int j = i >> 6, k = i & 63;
        WoT[k * 65 + j] = w_out[i];
    }
    __syncthreads();
    int w = tid >> 6, lane = tid & 63;
    float bj = b_out[lane];
    for (int n0 = blockIdx.x * 4; n0 < NN; n0 += gridDim.x * 4) {
        int n = n0 + w;
        if (n < NN) {
            vecs[w][lane] = h[(n << 6) + lane];
            WAVE_LDS_FENCE();
            float acc = bj;
            #pragma unroll 8
            for (int k = 0; k < HIDC; ++k)
                acc = fmaf(vecs[w][k], WoT[k * 65 + lane], acc);
            out[(n << 6) + lane] = acc;
        }
    }
}

extern "C" void kernel_launch(void* const* d_in, const int* in_sizes, int n_in,
                              void* d_out, int out_size, void* d_ws, size_t ws_size,
                              hipStream_t stream) {
    const float* x      = (const float*)d_in[0];
    const void*  ei     = d_in[1];
    const float* w_in   = (const float*)d_in[2];
    const float* b_in   = (const float*)d_in[3];
    const float* conv_w = (const float*)d_in[4];
    const float* w_out  = (const float*)d_in[5];
    const float* b_out  = (const float*)d_in[6];
    float* out = (float*)d_out;

    char* ws = (char*)d_ws;
    size_t off = 0;
    auto alloc = [&](size_t bytes) -> void* {
        void* p = ws + off;
        off += (bytes + 255) & ~(size_t)255;
        return p;
    };
    int*   flag    = (int*)alloc(4);
    int*   degi    = (int*)alloc((size_t)NN * 4);
    float* dinv    = (float*)alloc((size_t)NN * 4);
    int*   offsets = (int*)alloc((size_t)(NN + 1) * 4);
    int*   cursor  = (int*)alloc((size_t)NN * 4);
    int*   bsum    = (int*)alloc((size_t)SCAN_B * 4);
    int2*  adj     = (int2*)alloc((size_t)TOT * 8);
    float* hA      = (float*)alloc((size_t)NN * HIDC * 4);
    float* hB      = (float*)alloc((size_t)NN * HIDC * 4);
    float* x0      = (float*)alloc((size_t)NN * HIDC * 4);

    hipMemsetAsync(flag, 0, 4, stream);
    hipMemsetAsync(degi, 0, (size_t)NN * 4, stream);
    detect_kernel<<<256, 256, 0, stream>>>((const long long*)ei, flag);
    deg_kernel<<<(TOT + 255) / 256, 256, 0, stream>>>(ei, flag, degi);
    dinv_kernel<<<(NN + 255) / 256, 256, 0, stream>>>(degi, dinv);
    scan_part<<<SCAN_B, 256, 0, stream>>>(degi, bsum);
    scan_bsum<<<1, 256, 0, stream>>>(bsum);
    scan_final<<<SCAN_B, 256, 0, stream>>>(degi, bsum, offsets);
    hipMemcpyAsync(cursor, offsets, (size_t)NN * 4, hipMemcpyDeviceToDevice, stream);
    fill_kernel<<<(TOT + 255) / 256, 256, 0, stream>>>(ei, flag, dinv, cursor, adj);
    in_gemm<<<1024, 512, 0, stream>>>(x, w_in, b_in, hA, x0);

    float* cur = hA;
    float* nxt = hB;
    for (int l = 0; l < LLAYERS; ++l) {
        float beta = logf(0.5f / (float)(l + 1) + 1.0f);
        const float* Wl = conv_w + (size_t)l * HIDC * HIDC;
        layer_mid<<<2048, 256, 0, stream>>>(cur, nxt, x0, offsets, adj, Wl, beta);
        float* t = cur; cur = nxt; nxt = t;
    }
    out_gemm<<<1024, 256, 0, stream>>>(cur, w_out, b_out, out);
}